// Round 1
// baseline (6319.564 us; speedup 1.0000x reference)
//
#include <hip/hip_runtime.h>
#include <math.h>

// Swin block, B=32, H=W=64, C=384, heads=12, hd=32, WS=8, SS=4.
// 2048 windows x 64 tokens. fp32 baseline (no fp32 MFMA on CDNA4).

#define ROWS_TOTAL 131072   // 32*64*64 token rows
#define NWIN_TOTAL 2048

__device__ __forceinline__ int gather_row(int win, int t) {
  // token t of window win (shifted frame) -> original row index in x
  int b = win >> 6, wi = (win >> 3) & 7, wj = win & 7;
  int gi = (wi * 8 + (t >> 3) + 4) & 63;
  int gj = (wj * 8 + (t & 7) + 4) & 63;
  return (b << 12) + (gi << 6) + gj;
}

// ---------------- LN row stats: mean + rstd ----------------
extern "C" __global__ void ln_stats_k(const float* __restrict__ x,
                                      float* __restrict__ st) {
  int wid = threadIdx.x >> 6, lane = threadIdx.x & 63;
  int row = (blockIdx.x << 2) + wid;
  const float* p = x + (size_t)row * 384;
  float s = 0.f, ss = 0.f;
#pragma unroll
  for (int c = 0; c < 3; ++c) {
    float2 v = *(const float2*)(p + lane * 2 + c * 128);
    s += v.x + v.y;
    ss += v.x * v.x + v.y * v.y;
  }
#pragma unroll
  for (int o = 32; o > 0; o >>= 1) {
    s += __shfl_down(s, o);
    ss += __shfl_down(ss, o);
  }
  if (lane == 0) {
    float m = s * (1.f / 384.f);
    float var = ss * (1.f / 384.f) - m * m;
    *(float2*)(st + (size_t)row * 2) = make_float2(m, rsqrtf(var + 1e-5f));
  }
}

// ---------------- QKV GEMM: gathered+LN1 window tokens @ Wqkv ----------------
__global__ __launch_bounds__(256) void qkv_gemm_k(
    const float* __restrict__ x, const float* __restrict__ st,
    const float* __restrict__ g1, const float* __restrict__ b1,
    const float* __restrict__ W, const float* __restrict__ bias,
    float* __restrict__ qd, float* __restrict__ kd, float* __restrict__ vd,
    int wc0) {
  __shared__ __align__(16) float As[64][36];
  __shared__ __align__(16) float Bs[32][136];
  __shared__ int rowS[64];
  __shared__ float mS[64], rS[64];
  const int tid = threadIdx.x;
  const int w = blockIdx.x, win = wc0 + w;
  const int n0 = blockIdx.y * 128;
  if (tid < 64) {
    int gr = gather_row(win, tid);
    rowS[tid] = gr;
    float2 s2 = *(const float2*)(st + (size_t)gr * 2);
    mS[tid] = s2.x;
    rS[tid] = s2.y;
  }
  __syncthreads();
  const int ty = tid >> 4, tx = tid & 15;
  float acc[4][8];
#pragma unroll
  for (int i = 0; i < 4; ++i)
#pragma unroll
    for (int j = 0; j < 8; ++j) acc[i][j] = 0.f;

  for (int k0 = 0; k0 < 384; k0 += 32) {
#pragma unroll
    for (int sIt = 0; sIt < 2; ++sIt) {
      int id = tid + sIt * 256;
      int t = id >> 3, kc = (id & 7) << 2;
      float4 v = *(const float4*)(x + (size_t)rowS[t] * 384 + k0 + kc);
      float4 gg = *(const float4*)(g1 + k0 + kc);
      float4 bb = *(const float4*)(b1 + k0 + kc);
      float m = mS[t], r = rS[t];
      float4 o;
      o.x = (v.x - m) * r * gg.x + bb.x;
      o.y = (v.y - m) * r * gg.y + bb.y;
      o.z = (v.z - m) * r * gg.z + bb.z;
      o.w = (v.w - m) * r * gg.w + bb.w;
      *(float4*)&As[t][kc] = o;
    }
#pragma unroll
    for (int sIt = 0; sIt < 4; ++sIt) {
      int id = tid + sIt * 256;
      int rr = id >> 5, cc = (id & 31) << 2;
      *(float4*)&Bs[rr][cc] = *(const float4*)(W + (size_t)(k0 + rr) * 1152 + n0 + cc);
    }
    __syncthreads();
#pragma unroll
    for (int kk = 0; kk < 32; ++kk) {
      float av[4];
#pragma unroll
      for (int i = 0; i < 4; ++i) av[i] = As[ty * 4 + i][kk];
      float4 bA = *(float4*)&Bs[kk][tx * 4];
      float4 bB = *(float4*)&Bs[kk][64 + tx * 4];
      float bv[8] = {bA.x, bA.y, bA.z, bA.w, bB.x, bB.y, bB.z, bB.w};
#pragma unroll
      for (int i = 0; i < 4; ++i)
#pragma unroll
        for (int j = 0; j < 8; ++j) acc[i][j] = fmaf(av[i], bv[j], acc[i][j]);
    }
    __syncthreads();
  }
  const float scale = 0.17677669529663687f;  // 32^-0.5
#pragma unroll
  for (int i = 0; i < 4; ++i) {
    int t = ty * 4 + i;
#pragma unroll
    for (int half = 0; half < 2; ++half) {
      int nb = n0 + half * 64 + tx * 4;
      float4 bb = *(const float4*)(bias + nb);
      float4 o;
      o.x = acc[i][half * 4 + 0] + bb.x;
      o.y = acc[i][half * 4 + 1] + bb.y;
      o.z = acc[i][half * 4 + 2] + bb.z;
      o.w = acc[i][half * 4 + 3] + bb.w;
      int qi = nb / 384, rem = nb - qi * 384;
      int hh = rem >> 5, d = rem & 31;
      if (qi == 0) { o.x *= scale; o.y *= scale; o.z *= scale; o.w *= scale; }
      float* dst = (qi == 0 ? qd : (qi == 1 ? kd : vd)) +
                   ((((size_t)w * 12 + hh) * 64 + t) << 5) + d;
      *(float4*)dst = o;
    }
  }
}

// ---------------- windowed attention: one wave per (window, head) ----------------
__global__ __launch_bounds__(128) void attn_k(
    const float* __restrict__ q, const float* __restrict__ k,
    const float* __restrict__ v, const float* __restrict__ rpb,
    float* __restrict__ ao, int wc0) {
  __shared__ __align__(16) float kbuf[2][64][32];
  __shared__ __align__(16) float vbuf[2][64][32];
  __shared__ float bias[2][232];
  __shared__ int region[64];
  const int tid = threadIdx.x;
  const int wid = tid >> 6, lane = tid & 63;
  const int w = blockIdx.x, win = wc0 + w;
  const int head = blockIdx.y * 2 + wid;
  if (tid < 64) {
    int wi = (win >> 3) & 7, wj = win & 7;
    int pi = wi * 8 + (tid >> 3), pj = wj * 8 + (tid & 7);
    int ri = pi < 56 ? 0 : (pi < 60 ? 1 : 2);
    int rj = pj < 56 ? 0 : (pj < 60 ? 1 : 2);
    region[tid] = ri * 3 + rj;
  }
  const size_t hb = ((size_t)w * 12 + head) * 2048;  // *64*32
  const float* kp = k + hb;
  const float* vp = v + hb;
#pragma unroll
  for (int s = 0; s < 8; ++s) {
    int f = s * 64 + lane;
    int r = f >> 3, c = (f & 7) << 2;
    *(float4*)&kbuf[wid][r][c] = *(const float4*)(kp + r * 32 + c);
    *(float4*)&vbuf[wid][r][c] = *(const float4*)(vp + r * 32 + c);
  }
  for (int s = lane; s < 225; s += 64) bias[wid][s] = rpb[s * 12 + head];
  __syncthreads();
  const int i = lane;
  float qr[32];
  const float* qp = q + hb + (i << 5);
#pragma unroll
  for (int c = 0; c < 32; c += 4) {
    float4 t4 = *(const float4*)(qp + c);
    qr[c] = t4.x; qr[c + 1] = t4.y; qr[c + 2] = t4.z; qr[c + 3] = t4.w;
  }
  const int yi = i >> 3, xi = i & 7, regi = region[i];
  float sc[64];
  float mx = -3.0e38f;
#pragma unroll
  for (int j = 0; j < 64; ++j) {
    float a = 0.f;
#pragma unroll
    for (int c = 0; c < 32; c += 4) {
      float4 kv = *(float4*)&kbuf[wid][j][c];
      a = fmaf(qr[c], kv.x, a);
      a = fmaf(qr[c + 1], kv.y, a);
      a = fmaf(qr[c + 2], kv.z, a);
      a = fmaf(qr[c + 3], kv.w, a);
    }
    int dy = yi - (j >> 3) + 7, dx = xi - (j & 7) + 7;
    a += bias[wid][dy * 15 + dx];
    if (region[j] != regi) a -= 100.f;
    sc[j] = a;
    mx = fmaxf(mx, a);
  }
  float sum = 0.f;
#pragma unroll
  for (int j = 0; j < 64; ++j) {
    float e = __expf(sc[j] - mx);
    sc[j] = e;
    sum += e;
  }
  const float inv = 1.f / sum;
  float o[32];
#pragma unroll
  for (int c = 0; c < 32; ++c) o[c] = 0.f;
#pragma unroll
  for (int j = 0; j < 64; ++j) {
    float p = sc[j];
#pragma unroll
    for (int c = 0; c < 32; c += 4) {
      float4 vv = *(float4*)&vbuf[wid][j][c];
      o[c] = fmaf(p, vv.x, o[c]);
      o[c + 1] = fmaf(p, vv.y, o[c + 1]);
      o[c + 2] = fmaf(p, vv.z, o[c + 2]);
      o[c + 3] = fmaf(p, vv.w, o[c + 3]);
    }
  }
  float* op = ao + (size_t)(w * 64 + i) * 384 + (head << 5);
#pragma unroll
  for (int c = 0; c < 32; c += 4) {
    *(float4*)(op + c) =
        make_float4(o[c] * inv, o[c + 1] * inv, o[c + 2] * inv, o[c + 3] * inv);
  }
}

// ---------------- proj GEMM + un-shift scatter + shortcut add ----------------
__global__ __launch_bounds__(256) void proj_gemm_k(
    const float* __restrict__ A, const float* __restrict__ W,
    const float* __restrict__ pb, const float* __restrict__ x,
    float* __restrict__ x2, int wc0) {
  __shared__ __align__(16) float As[64][36];
  __shared__ __align__(16) float Bs[32][136];
  __shared__ int rowS[64];
  const int tid = threadIdx.x;
  const int w = blockIdx.x, win = wc0 + w;
  const int n0 = blockIdx.y * 128;
  if (tid < 64) rowS[tid] = gather_row(win, tid);
  __syncthreads();
  const int ty = tid >> 4, tx = tid & 15;
  float acc[4][8];
#pragma unroll
  for (int i = 0; i < 4; ++i)
#pragma unroll
    for (int j = 0; j < 8; ++j) acc[i][j] = 0.f;

  for (int k0 = 0; k0 < 384; k0 += 32) {
#pragma unroll
    for (int sIt = 0; sIt < 2; ++sIt) {
      int id = tid + sIt * 256;
      int t = id >> 3, kc = (id & 7) << 2;
      *(float4*)&As[t][kc] =
          *(const float4*)(A + (size_t)(w * 64 + t) * 384 + k0 + kc);
    }
#pragma unroll
    for (int sIt = 0; sIt < 4; ++sIt) {
      int id = tid + sIt * 256;
      int rr = id >> 5, cc = (id & 31) << 2;
      *(float4*)&Bs[rr][cc] = *(const float4*)(W + (size_t)(k0 + rr) * 384 + n0 + cc);
    }
    __syncthreads();
#pragma unroll
    for (int kk = 0; kk < 32; ++kk) {
      float av[4];
#pragma unroll
      for (int i = 0; i < 4; ++i) av[i] = As[ty * 4 + i][kk];
      float4 bA = *(float4*)&Bs[kk][tx * 4];
      float4 bB = *(float4*)&Bs[kk][64 + tx * 4];
      float bv[8] = {bA.x, bA.y, bA.z, bA.w, bB.x, bB.y, bB.z, bB.w};
#pragma unroll
      for (int i = 0; i < 4; ++i)
#pragma unroll
        for (int j = 0; j < 8; ++j) acc[i][j] = fmaf(av[i], bv[j], acc[i][j]);
    }
    __syncthreads();
  }
#pragma unroll
  for (int i = 0; i < 4; ++i) {
    int t = ty * 4 + i;
    int gr = rowS[t];
#pragma unroll
    for (int half = 0; half < 2; ++half) {
      int nb = n0 + half * 64 + tx * 4;
      float4 pb4 = *(const float4*)(pb + nb);
      float4 xs = *(const float4*)(x + (size_t)gr * 384 + nb);
      float4 o;
      o.x = acc[i][half * 4 + 0] + pb4.x + xs.x;
      o.y = acc[i][half * 4 + 1] + pb4.y + xs.y;
      o.z = acc[i][half * 4 + 2] + pb4.z + xs.z;
      o.w = acc[i][half * 4 + 3] + pb4.w + xs.w;
      *(float4*)(x2 + (size_t)gr * 384 + nb) = o;
    }
  }
}

// ---------------- fc1 GEMM with fused LN2 on A-load, GELU epilogue ----------------
__global__ __launch_bounds__(256) void fc1_gemm_k(
    const float* __restrict__ x2, const float* __restrict__ st,
    const float* __restrict__ g2, const float* __restrict__ b2,
    const float* __restrict__ W, const float* __restrict__ bias,
    float* __restrict__ hm, int row0) {
  __shared__ __align__(16) float As[64][36];
  __shared__ __align__(16) float Bs[32][136];
  __shared__ float mS[64], rS[64];
  const int tid = threadIdx.x;
  const int rbase = row0 + blockIdx.x * 64;
  const int n0 = blockIdx.y * 128;
  if (tid < 64) {
    float2 s2 = *(const float2*)(st + (size_t)(rbase + tid) * 2);
    mS[tid] = s2.x;
    rS[tid] = s2.y;
  }
  __syncthreads();
  const int ty = tid >> 4, tx = tid & 15;
  float acc[4][8];
#pragma unroll
  for (int i = 0; i < 4; ++i)
#pragma unroll
    for (int j = 0; j < 8; ++j) acc[i][j] = 0.f;

  for (int k0 = 0; k0 < 384; k0 += 32) {
#pragma unroll
    for (int sIt = 0; sIt < 2; ++sIt) {
      int id = tid + sIt * 256;
      int t = id >> 3, kc = (id & 7) << 2;
      float4 v = *(const float4*)(x2 + (size_t)(rbase + t) * 384 + k0 + kc);
      float4 gg = *(const float4*)(g2 + k0 + kc);
      float4 bb = *(const float4*)(b2 + k0 + kc);
      float m = mS[t], r = rS[t];
      float4 o;
      o.x = (v.x - m) * r * gg.x + bb.x;
      o.y = (v.y - m) * r * gg.y + bb.y;
      o.z = (v.z - m) * r * gg.z + bb.z;
      o.w = (v.w - m) * r * gg.w + bb.w;
      *(float4*)&As[t][kc] = o;
    }
#pragma unroll
    for (int sIt = 0; sIt < 4; ++sIt) {
      int id = tid + sIt * 256;
      int rr = id >> 5, cc = (id & 31) << 2;
      *(float4*)&Bs[rr][cc] = *(const float4*)(W + (size_t)(k0 + rr) * 1536 + n0 + cc);
    }
    __syncthreads();
#pragma unroll
    for (int kk = 0; kk < 32; ++kk) {
      float av[4];
#pragma unroll
      for (int i = 0; i < 4; ++i) av[i] = As[ty * 4 + i][kk];
      float4 bA = *(float4*)&Bs[kk][tx * 4];
      float4 bB = *(float4*)&Bs[kk][64 + tx * 4];
      float bv[8] = {bA.x, bA.y, bA.z, bA.w, bB.x, bB.y, bB.z, bB.w};
#pragma unroll
      for (int i = 0; i < 4; ++i)
#pragma unroll
        for (int j = 0; j < 8; ++j) acc[i][j] = fmaf(av[i], bv[j], acc[i][j]);
    }
    __syncthreads();
  }
#pragma unroll
  for (int i = 0; i < 4; ++i) {
    int lrow = blockIdx.x * 64 + ty * 4 + i;
#pragma unroll
    for (int half = 0; half < 2; ++half) {
      int nb = n0 + half * 64 + tx * 4;
      float4 bb = *(const float4*)(bias + nb);
      float4 o;
      o.x = acc[i][half * 4 + 0] + bb.x;
      o.y = acc[i][half * 4 + 1] + bb.y;
      o.z = acc[i][half * 4 + 2] + bb.z;
      o.w = acc[i][half * 4 + 3] + bb.w;
      o.x = 0.5f * o.x * (1.f + erff(o.x * 0.70710678118654752f));
      o.y = 0.5f * o.y * (1.f + erff(o.y * 0.70710678118654752f));
      o.z = 0.5f * o.z * (1.f + erff(o.z * 0.70710678118654752f));
      o.w = 0.5f * o.w * (1.f + erff(o.w * 0.70710678118654752f));
      *(float4*)(hm + (size_t)lrow * 1536 + nb) = o;
    }
  }
}

// ---------------- fc2 GEMM + residual into out (out already holds x2) ----------------
__global__ __launch_bounds__(256) void fc2_gemm_k(
    const float* __restrict__ hm, const float* __restrict__ W,
    const float* __restrict__ bias, float* out, int row0) {
  __shared__ __align__(16) float As[64][36];
  __shared__ __align__(16) float Bs[32][136];
  const int tid = threadIdx.x;
  const int n0 = blockIdx.y * 128;
  const int ty = tid >> 4, tx = tid & 15;
  float acc[4][8];
#pragma unroll
  for (int i = 0; i < 4; ++i)
#pragma unroll
    for (int j = 0; j < 8; ++j) acc[i][j] = 0.f;

  for (int k0 = 0; k0 < 1536; k0 += 32) {
#pragma unroll
    for (int sIt = 0; sIt < 2; ++sIt) {
      int id = tid + sIt * 256;
      int t = id >> 3, kc = (id & 7) << 2;
      *(float4*)&As[t][kc] =
          *(const float4*)(hm + (size_t)(blockIdx.x * 64 + t) * 1536 + k0 + kc);
    }
#pragma unroll
    for (int sIt = 0; sIt < 4; ++sIt) {
      int id = tid + sIt * 256;
      int rr = id >> 5, cc = (id & 31) << 2;
      *(float4*)&Bs[rr][cc] = *(const float4*)(W + (size_t)(k0 + rr) * 384 + n0 + cc);
    }
    __syncthreads();
#pragma unroll
    for (int kk = 0; kk < 32; ++kk) {
      float av[4];
#pragma unroll
      for (int i = 0; i < 4; ++i) av[i] = As[ty * 4 + i][kk];
      float4 bA = *(float4*)&Bs[kk][tx * 4];
      float4 bB = *(float4*)&Bs[kk][64 + tx * 4];
      float bv[8] = {bA.x, bA.y, bA.z, bA.w, bB.x, bB.y, bB.z, bB.w};
#pragma unroll
      for (int i = 0; i < 4; ++i)
#pragma unroll
        for (int j = 0; j < 8; ++j) acc[i][j] = fmaf(av[i], bv[j], acc[i][j]);
    }
    __syncthreads();
  }
#pragma unroll
  for (int i = 0; i < 4; ++i) {
    int grow = row0 + blockIdx.x * 64 + ty * 4 + i;
#pragma unroll
    for (int half = 0; half < 2; ++half) {
      int nb = n0 + half * 64 + tx * 4;
      float4 bb = *(const float4*)(bias + nb);
      float* dp = out + (size_t)grow * 384 + nb;
      float4 prev = *(float4*)dp;
      float4 o;
      o.x = acc[i][half * 4 + 0] + bb.x + prev.x;
      o.y = acc[i][half * 4 + 1] + bb.y + prev.y;
      o.z = acc[i][half * 4 + 2] + bb.z + prev.z;
      o.w = acc[i][half * 4 + 3] + bb.w + prev.w;
      *(float4*)dp = o;
    }
  }
}

extern "C" void kernel_launch(void* const* d_in, const int* in_sizes, int n_in,
                              void* d_out, int out_size, void* d_ws, size_t ws_size,
                              hipStream_t stream) {
  const float* x = (const float*)d_in[0];
  const float* qkv_w = (const float*)d_in[1];
  const float* qkv_b = (const float*)d_in[2];
  const float* proj_w = (const float*)d_in[3];
  const float* proj_b = (const float*)d_in[4];
  const float* rpb = (const float*)d_in[5];
  const float* n1g = (const float*)d_in[6];
  const float* n1b = (const float*)d_in[7];
  const float* n2g = (const float*)d_in[8];
  const float* n2b = (const float*)d_in[9];
  const float* fc1w = (const float*)d_in[10];
  const float* fc1b = (const float*)d_in[11];
  const float* fc2w = (const float*)d_in[12];
  const float* fc2b = (const float*)d_in[13];
  float* out = (float*)d_out;
  char* ws = (char*)d_ws;

  float* st1 = (float*)ws;
  float* st2 = (float*)(ws + (size_t)ROWS_TOTAL * 2 * sizeof(float));
  char* scratch = ws + (size_t)ROWS_TOTAL * 4 * sizeof(float);
  size_t ssz = ws_size - (size_t)ROWS_TOTAL * 4 * sizeof(float);

  float* x2 = out;  // x2 lives in d_out; fc2 adds MLP on top

  ln_stats_k<<<ROWS_TOTAL / 4, 256, 0, stream>>>(x, st1);

  // attention phase, chunked over windows to fit workspace
  const size_t perwin = (size_t)(3 * 24576 + 24576) * sizeof(float);  // q,k,v + attn_out
  int nwc = (int)(ssz / perwin);
  if (nwc > NWIN_TOTAL) nwc = NWIN_TOTAL;
  if (nwc < 1) nwc = 1;
  float* qd = (float*)scratch;
  float* kd = qd + (size_t)nwc * 24576;
  float* vd = kd + (size_t)nwc * 24576;
  float* ao = vd + (size_t)nwc * 24576;
  for (int wc0 = 0; wc0 < NWIN_TOTAL; wc0 += nwc) {
    int nw = (NWIN_TOTAL - wc0 < nwc) ? (NWIN_TOTAL - wc0) : nwc;
    qkv_gemm_k<<<dim3(nw, 9), 256, 0, stream>>>(x, st1, n1g, n1b, qkv_w, qkv_b,
                                                qd, kd, vd, wc0);
    attn_k<<<dim3(nw, 6), 128, 0, stream>>>(qd, kd, vd, rpb, ao, wc0);
    proj_gemm_k<<<dim3(nw, 3), 256, 0, stream>>>(ao, proj_w, proj_b, x, x2, wc0);
  }

  // MLP phase
  ln_stats_k<<<ROWS_TOTAL / 4, 256, 0, stream>>>(x2, st2);
  const size_t pergrp = (size_t)64 * 1536 * sizeof(float);
  int ngc = (int)(ssz / pergrp);
  if (ngc > 2048) ngc = 2048;
  if (ngc < 1) ngc = 1;
  float* hm = (float*)scratch;
  for (int g0 = 0; g0 < 2048; g0 += ngc) {
    int ng = (2048 - g0 < ngc) ? (2048 - g0) : ngc;
    fc1_gemm_k<<<dim3(ng, 12), 256, 0, stream>>>(x2, st2, n2g, n2b, fc1w, fc1b,
                                                 hm, g0 * 64);
    fc2_gemm_k<<<dim3(ng, 3), 256, 0, stream>>>(hm, fc2w, fc2b, out, g0 * 64);
  }
}

// Round 2
// 1669.473 us; speedup vs baseline: 3.7854x; 3.7854x over previous
//
#include <hip/hip_runtime.h>
#include <math.h>

// Swin block, B=32, H=W=64, C=384, heads=12, hd=32, WS=8, SS=4.
// Round 2: bf16 MFMA (16x16x32) for qkv/proj/fc1/fc2 GEMMs, fp32 accum.

#define ROWS_TOTAL 131072
#define NWIN_TOTAL 2048

typedef __attribute__((ext_vector_type(8))) __bf16 bf16x8;
typedef __attribute__((ext_vector_type(4))) float f32x4;
typedef __attribute__((ext_vector_type(8))) unsigned short ushort8;

__device__ __forceinline__ unsigned short f2bf(float f) {
  unsigned u = __builtin_bit_cast(unsigned, f);
  u = (u + 0x7fffu + ((u >> 16) & 1u)) >> 16;
  return (unsigned short)u;
}

__device__ __forceinline__ void gload16(const void* g, void* l) {
  __builtin_amdgcn_global_load_lds(
      (const __attribute__((address_space(1))) unsigned int*)g,
      (__attribute__((address_space(3))) unsigned int*)l, 16, 0, 0);
}

__device__ __forceinline__ int gather_row(int win, int t) {
  int b = win >> 6, wi = (win >> 3) & 7, wj = win & 7;
  int gi = (wi * 8 + (t >> 3) + 4) & 63;
  int gj = (wj * 8 + (t & 7) + 4) & 63;
  return (b << 12) + (gi << 6) + gj;
}

// fragment loads + 16 MFMA for one 32-deep K-step (wave tile 64x64)
__device__ __forceinline__ void frag_mma(const ushort* As_, const ushort* Bs_,
                                         int wr, int wc, int lane,
                                         f32x4 acc[4][4]) {
  const int lk = (lane >> 4) * 8, lr = lane & 15;
  bf16x8 af[4], bfr[4];
#pragma unroll
  for (int mi = 0; mi < 4; ++mi)
    af[mi] = *(const bf16x8*)(As_ + (wr * 64 + mi * 16 + lr) * 32 + lk);
#pragma unroll
  for (int nj = 0; nj < 4; ++nj)
    bfr[nj] = *(const bf16x8*)(Bs_ + (wc * 64 + nj * 16 + lr) * 32 + lk);
#pragma unroll
  for (int mi = 0; mi < 4; ++mi)
#pragma unroll
    for (int nj = 0; nj < 4; ++nj)
      acc[mi][nj] = __builtin_amdgcn_mfma_f32_16x16x32_bf16(
          af[mi], bfr[nj], acc[mi][nj], 0, 0, 0);
}

// ---------------- weight transpose+convert: W[k][n] f32 -> Wt[n][k] bf16 ----
__global__ __launch_bounds__(256) void wprep_k(
    const float* __restrict__ qkvw, const float* __restrict__ projw,
    const float* __restrict__ fc1w, const float* __restrict__ fc2w,
    ushort* __restrict__ wq, ushort* __restrict__ wp,
    ushort* __restrict__ w1, ushort* __restrict__ w2) {
  int gid = blockIdx.x * 256 + threadIdx.x;
  const int S1 = 1152 * 384;
  const int S2 = S1 + 384 * 384;
  const int S3 = S2 + 1536 * 384;
  const int S4 = S3 + 384 * 1536;
  if (gid < S1) {
    int n = gid / 384, k = gid - n * 384;
    wq[gid] = f2bf(qkvw[(size_t)k * 1152 + n]);
  } else if (gid < S2) {
    int i = gid - S1, n = i / 384, k = i - n * 384;
    wp[i] = f2bf(projw[(size_t)k * 384 + n]);
  } else if (gid < S3) {
    int i = gid - S2, n = i / 384, k = i - n * 384;
    w1[i] = f2bf(fc1w[(size_t)k * 1536 + n]);
  } else if (gid < S4) {
    int i = gid - S3, n = i / 1536, k = i - n * 1536;
    w2[i] = f2bf(fc2w[(size_t)k * 384 + n]);
  }
}

// ---------------- LN row stats ----------------
__global__ void ln_stats_k(const float* __restrict__ x, float* __restrict__ st) {
  int wid = threadIdx.x >> 6, lane = threadIdx.x & 63;
  int row = (blockIdx.x << 2) + wid;
  const float* p = x + (size_t)row * 384;
  float s = 0.f, ss = 0.f;
#pragma unroll
  for (int c = 0; c < 3; ++c) {
    float2 v = *(const float2*)(p + lane * 2 + c * 128);
    s += v.x + v.y;
    ss += v.x * v.x + v.y * v.y;
  }
#pragma unroll
  for (int o = 32; o > 0; o >>= 1) {
    s += __shfl_down(s, o);
    ss += __shfl_down(ss, o);
  }
  if (lane == 0) {
    float m = s * (1.f / 384.f);
    float var = ss * (1.f / 384.f) - m * m;
    *(float2*)(st + (size_t)row * 2) = make_float2(m, rsqrtf(var + 1e-5f));
  }
}

// ---------------- LN apply -> bf16 ----------------
__global__ __launch_bounds__(256) void ln_apply_k(
    const float* __restrict__ x, const float* __restrict__ st,
    const float* __restrict__ g, const float* __restrict__ b,
    ushort* __restrict__ o) {
  int gid = blockIdx.x * 256 + threadIdx.x;
  int row = gid / 48, c8 = (gid - row * 48) * 8;
  float2 s2 = *(const float2*)(st + (size_t)row * 2);
  const float* xp = x + (size_t)row * 384 + c8;
  float4 v0 = *(const float4*)xp, v1 = *(const float4*)(xp + 4);
  float4 g0 = *(const float4*)(g + c8), g1 = *(const float4*)(g + c8 + 4);
  float4 b0 = *(const float4*)(b + c8), b1 = *(const float4*)(b + c8 + 4);
  float m = s2.x, r = s2.y;
  ushort8 w;
  w[0] = f2bf((v0.x - m) * r * g0.x + b0.x);
  w[1] = f2bf((v0.y - m) * r * g0.y + b0.y);
  w[2] = f2bf((v0.z - m) * r * g0.z + b0.z);
  w[3] = f2bf((v0.w - m) * r * g0.w + b0.w);
  w[4] = f2bf((v1.x - m) * r * g1.x + b1.x);
  w[5] = f2bf((v1.y - m) * r * g1.y + b1.y);
  w[6] = f2bf((v1.z - m) * r * g1.z + b1.z);
  w[7] = f2bf((v1.w - m) * r * g1.w + b1.w);
  *(ushort8*)(o + (size_t)row * 384 + c8) = w;
}

// ---------------- QKV GEMM (bf16 MFMA): gathered xln @ WqT ----------------
__global__ __launch_bounds__(256) void qkv_mfma_k(
    const ushort* __restrict__ xln, const ushort* __restrict__ wq,
    const float* __restrict__ qkvb, float* __restrict__ qd,
    float* __restrict__ kd, float* __restrict__ vd, int wc0) {
  __shared__ __align__(16) ushort As[2][4096];
  __shared__ __align__(16) ushort Bs[2][4096];
  __shared__ int rowS[128];
  const int tid = threadIdx.x;
  const int w = tid >> 6, lane = tid & 63;
  const int wr = w >> 1, wc = w & 1;
  const int bm = blockIdx.x, n0 = blockIdx.y * 128;
  if (tid < 128) {
    int win = wc0 + bm * 2 + (tid >> 6);
    rowS[tid] = gather_row(win, tid & 63);
  }
  __syncthreads();
  const int rA = w * 32 + (lane >> 2);
  const char* aS0 = (const char*)xln + (size_t)rowS[rA] * 768 + (lane & 3) * 16;
  const char* aS1 = (const char*)xln + (size_t)rowS[rA + 16] * 768 + (lane & 3) * 16;
  const char* bS0 = (const char*)wq + (size_t)(n0 + rA) * 768 + (lane & 3) * 16;
  const char* bS1 = (const char*)wq + (size_t)(n0 + rA + 16) * 768 + (lane & 3) * 16;
  f32x4 acc[4][4];
#pragma unroll
  for (int i = 0; i < 4; ++i)
#pragma unroll
    for (int j = 0; j < 4; ++j) acc[i][j] = (f32x4)(0.f);
  int cur = 0;
#define STG(B_, T_)                                   \
  { size_t ko = (size_t)(T_) * 64;                    \
    gload16(aS0 + ko, &As[B_][w * 1024]);             \
    gload16(aS1 + ko, &As[B_][w * 1024 + 512]);       \
    gload16(bS0 + ko, &Bs[B_][w * 1024]);             \
    gload16(bS1 + ko, &Bs[B_][w * 1024 + 512]); }
  STG(0, 0);
  __syncthreads();
  for (int t = 0; t < 11; ++t) {
    STG(cur ^ 1, t + 1);
    frag_mma(As[cur], Bs[cur], wr, wc, lane, acc);
    __syncthreads();
    cur ^= 1;
  }
  frag_mma(As[cur], Bs[cur], wr, wc, lane, acc);
#undef STG
  const float scale = 0.17677669529663687f;
#pragma unroll
  for (int mi = 0; mi < 4; ++mi) {
#pragma unroll
    for (int r = 0; r < 4; ++r) {
      int rr = wr * 64 + mi * 16 + ((lane >> 4) << 2) + r;
      int w_rel = bm * 2 + (rr >> 6), t = rr & 63;
#pragma unroll
      for (int nj = 0; nj < 4; ++nj) {
        int nc = n0 + wc * 64 + nj * 16 + (lane & 15);
        float v = acc[mi][nj][r] + qkvb[nc];
        int qi = nc / 384, rem = nc - qi * 384;
        int hh = rem >> 5, d = rem & 31;
        float* base = (qi == 0) ? qd : (qi == 1 ? kd : vd);
        if (qi == 0) v *= scale;
        base[(((size_t)w_rel * 12 + hh) << 11) + (t << 5) + d] = v;
      }
    }
  }
}

// ---------------- windowed attention (fp32), emits bf16 ----------------
__global__ __launch_bounds__(128) void attn_k(
    const float* __restrict__ q, const float* __restrict__ k,
    const float* __restrict__ v, const float* __restrict__ rpb,
    ushort* __restrict__ ao, int wc0) {
  __shared__ __align__(16) float kbuf[2][64][32];
  __shared__ __align__(16) float vbuf[2][64][32];
  __shared__ float bias[2][232];
  __shared__ int region[64];
  const int tid = threadIdx.x;
  const int wid = tid >> 6, lane = tid & 63;
  const int w = blockIdx.x, win = wc0 + w;
  const int head = blockIdx.y * 2 + wid;
  if (tid < 64) {
    int wi = (win >> 3) & 7, wj = win & 7;
    int pi = wi * 8 + (tid >> 3), pj = wj * 8 + (tid & 7);
    int ri = pi < 56 ? 0 : (pi < 60 ? 1 : 2);
    int rj = pj < 56 ? 0 : (pj < 60 ? 1 : 2);
    region[tid] = ri * 3 + rj;
  }
  const size_t hb = ((size_t)w * 12 + head) * 2048;
  const float* kp = k + hb;
  const float* vp = v + hb;
#pragma unroll
  for (int s = 0; s < 8; ++s) {
    int f = s * 64 + lane;
    int r = f >> 3, c = (f & 7) << 2;
    *(float4*)&kbuf[wid][r][c] = *(const float4*)(kp + r * 32 + c);
    *(float4*)&vbuf[wid][r][c] = *(const float4*)(vp + r * 32 + c);
  }
  for (int s = lane; s < 225; s += 64) bias[wid][s] = rpb[s * 12 + head];
  __syncthreads();
  const int i = lane;
  float qr[32];
  const float* qp = q + hb + (i << 5);
#pragma unroll
  for (int c = 0; c < 32; c += 4) {
    float4 t4 = *(const float4*)(qp + c);
    qr[c] = t4.x; qr[c + 1] = t4.y; qr[c + 2] = t4.z; qr[c + 3] = t4.w;
  }
  const int yi = i >> 3, xi = i & 7, regi = region[i];
  float sc[64];
  float mx = -3.0e38f;
#pragma unroll
  for (int j = 0; j < 64; ++j) {
    float a = 0.f;
#pragma unroll
    for (int c = 0; c < 32; c += 4) {
      float4 kv = *(float4*)&kbuf[wid][j][c];
      a = fmaf(qr[c], kv.x, a);
      a = fmaf(qr[c + 1], kv.y, a);
      a = fmaf(qr[c + 2], kv.z, a);
      a = fmaf(qr[c + 3], kv.w, a);
    }
    int dy = yi - (j >> 3) + 7, dx = xi - (j & 7) + 7;
    a += bias[wid][dy * 15 + dx];
    if (region[j] != regi) a -= 100.f;
    sc[j] = a;
    mx = fmaxf(mx, a);
  }
  float sum = 0.f;
#pragma unroll
  for (int j = 0; j < 64; ++j) {
    float e = __expf(sc[j] - mx);
    sc[j] = e;
    sum += e;
  }
  const float inv = 1.f / sum;
  float o[32];
#pragma unroll
  for (int c = 0; c < 32; ++c) o[c] = 0.f;
#pragma unroll
  for (int j = 0; j < 64; ++j) {
    float p = sc[j];
#pragma unroll
    for (int c = 0; c < 32; c += 4) {
      float4 vv = *(float4*)&vbuf[wid][j][c];
      o[c] = fmaf(p, vv.x, o[c]);
      o[c + 1] = fmaf(p, vv.y, o[c + 1]);
      o[c + 2] = fmaf(p, vv.z, o[c + 2]);
      o[c + 3] = fmaf(p, vv.w, o[c + 3]);
    }
  }
  ushort* op = ao + ((size_t)(w * 64 + i)) * 384 + (head << 5);
#pragma unroll
  for (int c = 0; c < 32; c += 8) {
    ushort8 pk;
#pragma unroll
    for (int j2 = 0; j2 < 8; ++j2) pk[j2] = f2bf(o[c + j2] * inv);
    *(ushort8*)(op + c) = pk;
  }
}

// ---------------- proj GEMM (bf16 MFMA) + unshift scatter + residual --------
__global__ __launch_bounds__(256) void proj_mfma_k(
    const ushort* __restrict__ ao, const ushort* __restrict__ wp,
    const float* __restrict__ pb, const float* __restrict__ x,
    float* __restrict__ x2, int wc0) {
  __shared__ __align__(16) ushort As[2][4096];
  __shared__ __align__(16) ushort Bs[2][4096];
  const int tid = threadIdx.x;
  const int w = tid >> 6, lane = tid & 63;
  const int wr = w >> 1, wc = w & 1;
  const int bm = blockIdx.x, n0 = blockIdx.y * 128;
  const int rA = w * 32 + (lane >> 2);
  const char* aS0 = (const char*)ao + (size_t)(bm * 128 + rA) * 768 + (lane & 3) * 16;
  const char* aS1 = aS0 + (size_t)16 * 768;
  const char* bS0 = (const char*)wp + (size_t)(n0 + rA) * 768 + (lane & 3) * 16;
  const char* bS1 = bS0 + (size_t)16 * 768;
  f32x4 acc[4][4];
#pragma unroll
  for (int i = 0; i < 4; ++i)
#pragma unroll
    for (int j = 0; j < 4; ++j) acc[i][j] = (f32x4)(0.f);
  int cur = 0;
#define STG(B_, T_)                                   \
  { size_t ko = (size_t)(T_) * 64;                    \
    gload16(aS0 + ko, &As[B_][w * 1024]);             \
    gload16(aS1 + ko, &As[B_][w * 1024 + 512]);       \
    gload16(bS0 + ko, &Bs[B_][w * 1024]);             \
    gload16(bS1 + ko, &Bs[B_][w * 1024 + 512]); }
  STG(0, 0);
  __syncthreads();
  for (int t = 0; t < 11; ++t) {
    STG(cur ^ 1, t + 1);
    frag_mma(As[cur], Bs[cur], wr, wc, lane, acc);
    __syncthreads();
    cur ^= 1;
  }
  frag_mma(As[cur], Bs[cur], wr, wc, lane, acc);
#undef STG
#pragma unroll
  for (int mi = 0; mi < 4; ++mi) {
#pragma unroll
    for (int r = 0; r < 4; ++r) {
      int rr = wr * 64 + mi * 16 + ((lane >> 4) << 2) + r;
      int lw = (bm * 128 + rr) >> 6, t = rr & 63;
      int gr = gather_row(wc0 + lw, t);
#pragma unroll
      for (int nj = 0; nj < 4; ++nj) {
        int nc = n0 + wc * 64 + nj * 16 + (lane & 15);
        size_t idx = (size_t)gr * 384 + nc;
        x2[idx] = acc[mi][nj][r] + pb[nc] + x[idx];
      }
    }
  }
}

// ---------------- fc1 GEMM (bf16 MFMA) + GELU -> bf16 hm ----------------
__global__ __launch_bounds__(256) void fc1_mfma_k(
    const ushort* __restrict__ x2ln, const ushort* __restrict__ w1,
    const float* __restrict__ fb, ushort* __restrict__ hm, int row0) {
  __shared__ __align__(16) ushort As[2][4096];
  __shared__ __align__(16) ushort Bs[2][4096];
  const int tid = threadIdx.x;
  const int w = tid >> 6, lane = tid & 63;
  const int wr = w >> 1, wc = w & 1;
  const int bm = blockIdx.x, n0 = blockIdx.y * 128;
  const int rA = w * 32 + (lane >> 2);
  const char* aS0 = (const char*)x2ln + (size_t)(row0 + bm * 128 + rA) * 768 + (lane & 3) * 16;
  const char* aS1 = aS0 + (size_t)16 * 768;
  const char* bS0 = (const char*)w1 + (size_t)(n0 + rA) * 768 + (lane & 3) * 16;
  const char* bS1 = bS0 + (size_t)16 * 768;
  f32x4 acc[4][4];
#pragma unroll
  for (int i = 0; i < 4; ++i)
#pragma unroll
    for (int j = 0; j < 4; ++j) acc[i][j] = (f32x4)(0.f);
  int cur = 0;
#define STG(B_, T_)                                   \
  { size_t ko = (size_t)(T_) * 64;                    \
    gload16(aS0 + ko, &As[B_][w * 1024]);             \
    gload16(aS1 + ko, &As[B_][w * 1024 + 512]);       \
    gload16(bS0 + ko, &Bs[B_][w * 1024]);             \
    gload16(bS1 + ko, &Bs[B_][w * 1024 + 512]); }
  STG(0, 0);
  __syncthreads();
  for (int t = 0; t < 11; ++t) {
    STG(cur ^ 1, t + 1);
    frag_mma(As[cur], Bs[cur], wr, wc, lane, acc);
    __syncthreads();
    cur ^= 1;
  }
  frag_mma(As[cur], Bs[cur], wr, wc, lane, acc);
#undef STG
#pragma unroll
  for (int mi = 0; mi < 4; ++mi) {
#pragma unroll
    for (int r = 0; r < 4; ++r) {
      int rr = wr * 64 + mi * 16 + ((lane >> 4) << 2) + r;
      size_t lrow = (size_t)(bm * 128 + rr);
#pragma unroll
      for (int nj = 0; nj < 4; ++nj) {
        int nc = n0 + wc * 64 + nj * 16 + (lane & 15);
        float v = acc[mi][nj][r] + fb[nc];
        v = 0.5f * v * (1.f + erff(v * 0.70710678118654752f));
        hm[lrow * 1536 + nc] = f2bf(v);
      }
    }
  }
}

// ---------------- fc2 GEMM (bf16 MFMA) + residual into out ----------------
__global__ __launch_bounds__(256) void fc2_mfma_k(
    const ushort* __restrict__ hm, const ushort* __restrict__ w2,
    const float* __restrict__ fb, float* __restrict__ out, int row0) {
  __shared__ __align__(16) ushort As[2][4096];
  __shared__ __align__(16) ushort Bs[2][4096];
  const int tid = threadIdx.x;
  const int w = tid >> 6, lane = tid & 63;
  const int wr = w >> 1, wc = w & 1;
  const int bm = blockIdx.x, n0 = blockIdx.y * 128;
  const int rA = w * 32 + (lane >> 2);
  const char* aS0 = (const char*)hm + (size_t)(bm * 128 + rA) * 3072 + (lane & 3) * 16;
  const char* aS1 = aS0 + (size_t)16 * 3072;
  const char* bS0 = (const char*)w2 + (size_t)(n0 + rA) * 3072 + (lane & 3) * 16;
  const char* bS1 = bS0 + (size_t)16 * 3072;
  f32x4 acc[4][4];
#pragma unroll
  for (int i = 0; i < 4; ++i)
#pragma unroll
    for (int j = 0; j < 4; ++j) acc[i][j] = (f32x4)(0.f);
  int cur = 0;
#define STG(B_, T_)                                   \
  { size_t ko = (size_t)(T_) * 64;                    \
    gload16(aS0 + ko, &As[B_][w * 1024]);             \
    gload16(aS1 + ko, &As[B_][w * 1024 + 512]);       \
    gload16(bS0 + ko, &Bs[B_][w * 1024]);             \
    gload16(bS1 + ko, &Bs[B_][w * 1024 + 512]); }
  STG(0, 0);
  __syncthreads();
  for (int t = 0; t < 47; ++t) {
    STG(cur ^ 1, t + 1);
    frag_mma(As[cur], Bs[cur], wr, wc, lane, acc);
    __syncthreads();
    cur ^= 1;
  }
  frag_mma(As[cur], Bs[cur], wr, wc, lane, acc);
#undef STG
#pragma unroll
  for (int mi = 0; mi < 4; ++mi) {
#pragma unroll
    for (int r = 0; r < 4; ++r) {
      int rr = wr * 64 + mi * 16 + ((lane >> 4) << 2) + r;
      size_t grow = (size_t)(row0 + bm * 128 + rr);
#pragma unroll
      for (int nj = 0; nj < 4; ++nj) {
        int nc = n0 + wc * 64 + nj * 16 + (lane & 15);
        size_t idx = grow * 384 + nc;
        out[idx] = out[idx] + acc[mi][nj][r] + fb[nc];
      }
    }
  }
}

extern "C" void kernel_launch(void* const* d_in, const int* in_sizes, int n_in,
                              void* d_out, int out_size, void* d_ws, size_t ws_size,
                              hipStream_t stream) {
  const float* x = (const float*)d_in[0];
  const float* qkv_w = (const float*)d_in[1];
  const float* qkv_b = (const float*)d_in[2];
  const float* proj_w = (const float*)d_in[3];
  const float* proj_b = (const float*)d_in[4];
  const float* rpb = (const float*)d_in[5];
  const float* n1g = (const float*)d_in[6];
  const float* n1b = (const float*)d_in[7];
  const float* n2g = (const float*)d_in[8];
  const float* n2b = (const float*)d_in[9];
  const float* fc1w = (const float*)d_in[10];
  const float* fc1b = (const float*)d_in[11];
  const float* fc2w = (const float*)d_in[12];
  const float* fc2b = (const float*)d_in[13];
  float* out = (float*)d_out;
  char* ws = (char*)d_ws;

  float* st1 = (float*)ws;                               // 1 MB
  float* st2 = (float*)(ws + 1048576);                   // 1 MB
  ushort* wq = (ushort*)(ws + 2097152);                  // [1152][384]
  ushort* wp = wq + 442368;                              // [384][384]
  ushort* w1 = wp + 147456;                              // [1536][384]
  ushort* w2 = w1 + 589824;                              // [384][1536]
  ushort* xln = (ushort*)(ws + 5636096);                 // 100663296 B
  char* scratch = ws + 5636096 + 100663296;
  size_t base = 5636096 + 100663296;
  size_t ssz = (ws_size > base) ? ws_size - base : 0;

  wprep_k<<<6912, 256, 0, stream>>>(qkv_w, proj_w, fc1w, fc2w, wq, wp, w1, w2);
  ln_stats_k<<<ROWS_TOTAL / 4, 256, 0, stream>>>(x, st1);
  ln_apply_k<<<ROWS_TOTAL * 48 / 256, 256, 0, stream>>>(x, st1, n1g, n1b, xln);

  // attention phase, chunked over windows
  const size_t perwin = 344064;  // q,k,v fp32 (3*98304B) + ao bf16 (49152B)
  int nwc = (int)(ssz / perwin);
  if (nwc > NWIN_TOTAL) nwc = NWIN_TOTAL;
  nwc &= ~1;
  if (nwc < 2) nwc = 2;
  float* qd = (float*)scratch;
  float* kd = qd + (size_t)nwc * 24576;
  float* vd = kd + (size_t)nwc * 24576;
  ushort* ao = (ushort*)(vd + (size_t)nwc * 24576);
  for (int wc0 = 0; wc0 < NWIN_TOTAL; wc0 += nwc) {
    int nw = (NWIN_TOTAL - wc0 < nwc) ? (NWIN_TOTAL - wc0) : nwc;
    qkv_mfma_k<<<dim3(nw / 2, 9), 256, 0, stream>>>(xln, wq, qkv_b, qd, kd, vd, wc0);
    attn_k<<<dim3(nw, 6), 128, 0, stream>>>(qd, kd, vd, rpb, ao, wc0);
    proj_mfma_k<<<dim3(nw / 2, 3), 256, 0, stream>>>(ao, wp, proj_b, x, out, wc0);
  }

  // MLP phase
  ln_stats_k<<<ROWS_TOTAL / 4, 256, 0, stream>>>(out, st2);
  ln_apply_k<<<ROWS_TOTAL * 48 / 256, 256, 0, stream>>>(out, st2, n2g, n2b, xln);
  const size_t pergrp = 393216;  // 128 rows * 1536 * 2B
  int ngc = (int)(ssz / pergrp);
  if (ngc > 1024) ngc = 1024;
  if (ngc < 1) ngc = 1;
  ushort* hm = (ushort*)scratch;
  for (int g0 = 0; g0 < 1024; g0 += ngc) {
    int ng = (1024 - g0 < ngc) ? (1024 - g0) : ngc;
    fc1_mfma_k<<<dim3(ng, 12), 256, 0, stream>>>(xln, w1, fc1b, hm, g0 * 128);
    fc2_mfma_k<<<dim3(ng, 3), 256, 0, stream>>>(hm, w2, fc2b, out, g0 * 128);
  }
}

// Round 3
// 1573.730 us; speedup vs baseline: 4.0157x; 1.0608x over previous
//
#include <hip/hip_runtime.h>
#include <math.h>

// Swin block, B=32, H=W=64, C=384, heads=12, hd=32, WS=8, SS=4.
// Round 3: swizzled LDS (conflict-free) + 3-deep pipeline, raw s_barrier +
// counted vmcnt(4) (T3/T4) + setprio (T5) on all four bf16-MFMA GEMMs.

#define ROWS_TOTAL 131072
#define NWIN_TOTAL 2048

typedef __attribute__((ext_vector_type(8))) __bf16 bf16x8;
typedef __attribute__((ext_vector_type(4))) float f32x4;
typedef __attribute__((ext_vector_type(8))) unsigned short ushort8;

__device__ __forceinline__ unsigned short f2bf(float f) {
  unsigned u = __builtin_bit_cast(unsigned, f);
  u = (u + 0x7fffu + ((u >> 16) & 1u)) >> 16;
  return (unsigned short)u;
}

__device__ __forceinline__ void gload16(const void* g, void* l) {
  __builtin_amdgcn_global_load_lds(
      (const __attribute__((address_space(1))) unsigned int*)g,
      (__attribute__((address_space(3))) unsigned int*)l, 16, 0, 0);
}

__device__ __forceinline__ int gather_row(int win, int t) {
  int b = win >> 6, wi = (win >> 3) & 7, wj = win & 7;
  int gi = (wi * 8 + (t >> 3) + 4) & 63;
  int gj = (wj * 8 + (t & 7) + 4) & 63;
  return (b << 12) + (gi << 6) + gj;
}

// Fragment loads (swizzled) + 16 MFMA for one 32-deep K-step (wave tile 64x64).
// LDS layout: row-major [128][32 bf16] (64B rows); granule slot s of row r
// holds logical 16B granule s ^ ((r>>1)&3)  -> conflict-free ds_read_b128.
__device__ __forceinline__ void frag_mma(const ushort* As_, const ushort* Bs_,
                                         int wr, int wc, int lane,
                                         f32x4 acc[4][4]) {
  const int go = (((lane >> 4) ^ ((lane >> 1) & 3)) << 3);  // swizzled, ushorts
  const int lr = lane & 15;
  bf16x8 af[4], bfr[4];
#pragma unroll
  for (int mi = 0; mi < 4; ++mi)
    af[mi] = *(const bf16x8*)(As_ + (wr * 64 + mi * 16 + lr) * 32 + go);
#pragma unroll
  for (int nj = 0; nj < 4; ++nj)
    bfr[nj] = *(const bf16x8*)(Bs_ + (wc * 64 + nj * 16 + lr) * 32 + go);
#pragma unroll
  for (int mi = 0; mi < 4; ++mi)
#pragma unroll
    for (int nj = 0; nj < 4; ++nj)
      acc[mi][nj] = __builtin_amdgcn_mfma_f32_16x16x32_bf16(
          af[mi], bfr[nj], acc[mi][nj], 0, 0, 0);
}

#define VM4() asm volatile("s_waitcnt vmcnt(4)" ::: "memory")
#define VM0() asm volatile("s_waitcnt vmcnt(0)" ::: "memory")
#define SCB() __builtin_amdgcn_sched_barrier(0)
#define BARR() __builtin_amdgcn_s_barrier()

// per-wave stage of one 32-deep K-step into buffer B_: 2x A rows, 2x B rows.
// LDS dest linear (gload requirement); global src carries the inverse swizzle
// (sle below), so LDS holds the swizzled layout frag_mma expects.
#define STG(B_, T_)                                   \
  { size_t ko = (size_t)(T_) * 64;                    \
    gload16(aS0 + ko, &As[B_][w * 1024]);             \
    gload16(aS1 + ko, &As[B_][w * 1024 + 512]);       \
    gload16(bS0 + ko, &Bs[B_][w * 1024]);             \
    gload16(bS1 + ko, &Bs[B_][w * 1024 + 512]); }

#define GEMM_PIPE(NK)                                               \
  {                                                                 \
    STG(0, 0);                                                      \
    STG(1, 1);                                                      \
    VM4(); SCB(); BARR(); SCB();                                    \
    int cur = 0;                                                    \
    for (int t = 0; t < (NK); ++t) {                                \
      if (t + 2 < (NK)) {                                           \
        int nb = cur + 2; if (nb >= 3) nb -= 3;                     \
        STG(nb, t + 2);                                             \
      }                                                             \
      __builtin_amdgcn_s_setprio(1);                                \
      frag_mma(&As[cur][0], &Bs[cur][0], wr, wc, lane, acc);        \
      __builtin_amdgcn_s_setprio(0);                                \
      if (t + 2 < (NK)) { VM4(); } else { VM0(); }                  \
      SCB(); BARR(); SCB();                                         \
      ++cur; if (cur == 3) cur = 0;                                 \
    }                                                               \
  }

// ---------------- weight transpose+convert: W[k][n] f32 -> Wt[n][k] bf16 ----
__global__ __launch_bounds__(256) void wprep_k(
    const float* __restrict__ qkvw, const float* __restrict__ projw,
    const float* __restrict__ fc1w, const float* __restrict__ fc2w,
    ushort* __restrict__ wq, ushort* __restrict__ wp,
    ushort* __restrict__ w1, ushort* __restrict__ w2) {
  int gid = blockIdx.x * 256 + threadIdx.x;
  const int S1 = 1152 * 384;
  const int S2 = S1 + 384 * 384;
  const int S3 = S2 + 1536 * 384;
  const int S4 = S3 + 384 * 1536;
  if (gid < S1) {
    int n = gid / 384, k = gid - n * 384;
    wq[gid] = f2bf(qkvw[(size_t)k * 1152 + n]);
  } else if (gid < S2) {
    int i = gid - S1, n = i / 384, k = i - n * 384;
    wp[i] = f2bf(projw[(size_t)k * 384 + n]);
  } else if (gid < S3) {
    int i = gid - S2, n = i / 384, k = i - n * 384;
    w1[i] = f2bf(fc1w[(size_t)k * 1536 + n]);
  } else if (gid < S4) {
    int i = gid - S3, n = i / 1536, k = i - n * 1536;
    w2[i] = f2bf(fc2w[(size_t)k * 384 + n]);
  }
}

// ---------------- LN row stats ----------------
__global__ void ln_stats_k(const float* __restrict__ x, float* __restrict__ st) {
  int wid = threadIdx.x >> 6, lane = threadIdx.x & 63;
  int row = (blockIdx.x << 2) + wid;
  const float* p = x + (size_t)row * 384;
  float s = 0.f, ss = 0.f;
#pragma unroll
  for (int c = 0; c < 3; ++c) {
    float2 v = *(const float2*)(p + lane * 2 + c * 128);
    s += v.x + v.y;
    ss += v.x * v.x + v.y * v.y;
  }
#pragma unroll
  for (int o = 32; o > 0; o >>= 1) {
    s += __shfl_down(s, o);
    ss += __shfl_down(ss, o);
  }
  if (lane == 0) {
    float m = s * (1.f / 384.f);
    float var = ss * (1.f / 384.f) - m * m;
    *(float2*)(st + (size_t)row * 2) = make_float2(m, rsqrtf(var + 1e-5f));
  }
}

// ---------------- LN apply -> bf16 ----------------
__global__ __launch_bounds__(256) void ln_apply_k(
    const float* __restrict__ x, const float* __restrict__ st,
    const float* __restrict__ g, const float* __restrict__ b,
    ushort* __restrict__ o) {
  int gid = blockIdx.x * 256 + threadIdx.x;
  int row = gid / 48, c8 = (gid - row * 48) * 8;
  float2 s2 = *(const float2*)(st + (size_t)row * 2);
  const float* xp = x + (size_t)row * 384 + c8;
  float4 v0 = *(const float4*)xp, v1 = *(const float4*)(xp + 4);
  float4 g0 = *(const float4*)(g + c8), g1 = *(const float4*)(g + c8 + 4);
  float4 b0 = *(const float4*)(b + c8), b1 = *(const float4*)(b + c8 + 4);
  float m = s2.x, r = s2.y;
  ushort8 w;
  w[0] = f2bf((v0.x - m) * r * g0.x + b0.x);
  w[1] = f2bf((v0.y - m) * r * g0.y + b0.y);
  w[2] = f2bf((v0.z - m) * r * g0.z + b0.z);
  w[3] = f2bf((v0.w - m) * r * g0.w + b0.w);
  w[4] = f2bf((v1.x - m) * r * g1.x + b1.x);
  w[5] = f2bf((v1.y - m) * r * g1.y + b1.y);
  w[6] = f2bf((v1.z - m) * r * g1.z + b1.z);
  w[7] = f2bf((v1.w - m) * r * g1.w + b1.w);
  *(ushort8*)(o + (size_t)row * 384 + c8) = w;
}

// ---------------- QKV GEMM (bf16 MFMA): gathered xln @ WqT ----------------
__global__ __launch_bounds__(256) void qkv_mfma_k(
    const ushort* __restrict__ xln, const ushort* __restrict__ wq,
    const float* __restrict__ qkvb, float* __restrict__ qd,
    float* __restrict__ kd, float* __restrict__ vd, int wc0) {
  __shared__ __align__(16) ushort As[3][4096];
  __shared__ __align__(16) ushort Bs[3][4096];
  __shared__ int rowS[128];
  const int tid = threadIdx.x;
  const int w = tid >> 6, lane = tid & 63;
  const int wr = w >> 1, wc = w & 1;
  const int bm = blockIdx.x, n0 = blockIdx.y * 128;
  if (tid < 128) {
    int win = wc0 + bm * 2 + (tid >> 6);
    rowS[tid] = gather_row(win, tid & 63);
  }
  __syncthreads();
  const int rA = w * 32 + (lane >> 2);
  const int sle = (((lane & 3) ^ ((lane >> 3) & 3)) << 4);  // swizzled src slot
  const char* aS0 = (const char*)xln + (size_t)rowS[rA] * 768 + sle;
  const char* aS1 = (const char*)xln + (size_t)rowS[rA + 16] * 768 + sle;
  const char* bS0 = (const char*)wq + (size_t)(n0 + rA) * 768 + sle;
  const char* bS1 = (const char*)wq + (size_t)(n0 + rA + 16) * 768 + sle;
  f32x4 acc[4][4];
#pragma unroll
  for (int i = 0; i < 4; ++i)
#pragma unroll
    for (int j = 0; j < 4; ++j) acc[i][j] = (f32x4)(0.f);
  GEMM_PIPE(12);
  const float scale = 0.17677669529663687f;
#pragma unroll
  for (int mi = 0; mi < 4; ++mi) {
#pragma unroll
    for (int r = 0; r < 4; ++r) {
      int rr = wr * 64 + mi * 16 + ((lane >> 4) << 2) + r;
      int w_rel = bm * 2 + (rr >> 6), t = rr & 63;
#pragma unroll
      for (int nj = 0; nj < 4; ++nj) {
        int nc = n0 + wc * 64 + nj * 16 + (lane & 15);
        float v = acc[mi][nj][r] + qkvb[nc];
        int qi = nc / 384, rem = nc - qi * 384;
        int hh = rem >> 5, d = rem & 31;
        float* base = (qi == 0) ? qd : (qi == 1 ? kd : vd);
        if (qi == 0) v *= scale;
        base[(((size_t)w_rel * 12 + hh) << 11) + (t << 5) + d] = v;
      }
    }
  }
}

// ---------------- windowed attention (fp32), emits bf16 ----------------
__global__ __launch_bounds__(128) void attn_k(
    const float* __restrict__ q, const float* __restrict__ k,
    const float* __restrict__ v, const float* __restrict__ rpb,
    ushort* __restrict__ ao, int wc0) {
  __shared__ __align__(16) float kbuf[2][64][32];
  __shared__ __align__(16) float vbuf[2][64][32];
  __shared__ float bias[2][232];
  __shared__ int region[64];
  const int tid = threadIdx.x;
  const int wid = tid >> 6, lane = tid & 63;
  const int w = blockIdx.x, win = wc0 + w;
  const int head = blockIdx.y * 2 + wid;
  if (tid < 64) {
    int wi = (win >> 3) & 7, wj = win & 7;
    int pi = wi * 8 + (tid >> 3), pj = wj * 8 + (tid & 7);
    int ri = pi < 56 ? 0 : (pi < 60 ? 1 : 2);
    int rj = pj < 56 ? 0 : (pj < 60 ? 1 : 2);
    region[tid] = ri * 3 + rj;
  }
  const size_t hb = ((size_t)w * 12 + head) * 2048;
  const float* kp = k + hb;
  const float* vp = v + hb;
#pragma unroll
  for (int s = 0; s < 8; ++s) {
    int f = s * 64 + lane;
    int r = f >> 3, c = (f & 7) << 2;
    *(float4*)&kbuf[wid][r][c] = *(const float4*)(kp + r * 32 + c);
    *(float4*)&vbuf[wid][r][c] = *(const float4*)(vp + r * 32 + c);
  }
  for (int s = lane; s < 225; s += 64) bias[wid][s] = rpb[s * 12 + head];
  __syncthreads();
  const int i = lane;
  float qr[32];
  const float* qp = q + hb + (i << 5);
#pragma unroll
  for (int c = 0; c < 32; c += 4) {
    float4 t4 = *(const float4*)(qp + c);
    qr[c] = t4.x; qr[c + 1] = t4.y; qr[c + 2] = t4.z; qr[c + 3] = t4.w;
  }
  const int yi = i >> 3, xi = i & 7, regi = region[i];
  float sc[64];
  float mx = -3.0e38f;
#pragma unroll
  for (int j = 0; j < 64; ++j) {
    float a = 0.f;
#pragma unroll
    for (int c = 0; c < 32; c += 4) {
      float4 kv = *(float4*)&kbuf[wid][j][c];
      a = fmaf(qr[c], kv.x, a);
      a = fmaf(qr[c + 1], kv.y, a);
      a = fmaf(qr[c + 2], kv.z, a);
      a = fmaf(qr[c + 3], kv.w, a);
    }
    int dy = yi - (j >> 3) + 7, dx = xi - (j & 7) + 7;
    a += bias[wid][dy * 15 + dx];
    if (region[j] != regi) a -= 100.f;
    sc[j] = a;
    mx = fmaxf(mx, a);
  }
  float sum = 0.f;
#pragma unroll
  for (int j = 0; j < 64; ++j) {
    float e = __expf(sc[j] - mx);
    sc[j] = e;
    sum += e;
  }
  const float inv = 1.f / sum;
  float o[32];
#pragma unroll
  for (int c = 0; c < 32; ++c) o[c] = 0.f;
#pragma unroll
  for (int j = 0; j < 64; ++j) {
    float p = sc[j];
#pragma unroll
    for (int c = 0; c < 32; c += 4) {
      float4 vv = *(float4*)&vbuf[wid][j][c];
      o[c] = fmaf(p, vv.x, o[c]);
      o[c + 1] = fmaf(p, vv.y, o[c + 1]);
      o[c + 2] = fmaf(p, vv.z, o[c + 2]);
      o[c + 3] = fmaf(p, vv.w, o[c + 3]);
    }
  }
  ushort* op = ao + ((size_t)(w * 64 + i)) * 384 + (head << 5);
#pragma unroll
  for (int c = 0; c < 32; c += 8) {
    ushort8 pk;
#pragma unroll
    for (int j2 = 0; j2 < 8; ++j2) pk[j2] = f2bf(o[c + j2] * inv);
    *(ushort8*)(op + c) = pk;
  }
}

// ---------------- proj GEMM (bf16 MFMA) + unshift scatter + residual --------
__global__ __launch_bounds__(256) void proj_mfma_k(
    const ushort* __restrict__ ao, const ushort* __restrict__ wp,
    const float* __restrict__ pb, const float* __restrict__ x,
    float* __restrict__ x2, int wc0) {
  __shared__ __align__(16) ushort As[3][4096];
  __shared__ __align__(16) ushort Bs[3][4096];
  const int tid = threadIdx.x;
  const int w = tid >> 6, lane = tid & 63;
  const int wr = w >> 1, wc = w & 1;
  const int bm = blockIdx.x, n0 = blockIdx.y * 128;
  const int rA = w * 32 + (lane >> 2);
  const int sle = (((lane & 3) ^ ((lane >> 3) & 3)) << 4);
  const char* aS0 = (const char*)ao + (size_t)(bm * 128 + rA) * 768 + sle;
  const char* aS1 = aS0 + (size_t)16 * 768;
  const char* bS0 = (const char*)wp + (size_t)(n0 + rA) * 768 + sle;
  const char* bS1 = bS0 + (size_t)16 * 768;
  f32x4 acc[4][4];
#pragma unroll
  for (int i = 0; i < 4; ++i)
#pragma unroll
    for (int j = 0; j < 4; ++j) acc[i][j] = (f32x4)(0.f);
  GEMM_PIPE(12);
#pragma unroll
  for (int mi = 0; mi < 4; ++mi) {
#pragma unroll
    for (int r = 0; r < 4; ++r) {
      int rr = wr * 64 + mi * 16 + ((lane >> 4) << 2) + r;
      int lw = (bm * 128 + rr) >> 6, t = rr & 63;
      int gr = gather_row(wc0 + lw, t);
#pragma unroll
      for (int nj = 0; nj < 4; ++nj) {
        int nc = n0 + wc * 64 + nj * 16 + (lane & 15);
        size_t idx = (size_t)gr * 384 + nc;
        x2[idx] = acc[mi][nj][r] + pb[nc] + x[idx];
      }
    }
  }
}

// ---------------- fc1 GEMM (bf16 MFMA) + GELU -> bf16 hm ----------------
__global__ __launch_bounds__(256) void fc1_mfma_k(
    const ushort* __restrict__ x2ln, const ushort* __restrict__ w1,
    const float* __restrict__ fb, ushort* __restrict__ hm, int row0) {
  __shared__ __align__(16) ushort As[3][4096];
  __shared__ __align__(16) ushort Bs[3][4096];
  const int tid = threadIdx.x;
  const int w = tid >> 6, lane = tid & 63;
  const int wr = w >> 1, wc = w & 1;
  const int bm = blockIdx.x, n0 = blockIdx.y * 128;
  const int rA = w * 32 + (lane >> 2);
  const int sle = (((lane & 3) ^ ((lane >> 3) & 3)) << 4);
  const char* aS0 =
      (const char*)x2ln + (size_t)(row0 + bm * 128 + rA) * 768 + sle;
  const char* aS1 = aS0 + (size_t)16 * 768;
  const char* bS0 = (const char*)w1 + (size_t)(n0 + rA) * 768 + sle;
  const char* bS1 = bS0 + (size_t)16 * 768;
  f32x4 acc[4][4];
#pragma unroll
  for (int i = 0; i < 4; ++i)
#pragma unroll
    for (int j = 0; j < 4; ++j) acc[i][j] = (f32x4)(0.f);
  GEMM_PIPE(12);
#pragma unroll
  for (int mi = 0; mi < 4; ++mi) {
#pragma unroll
    for (int r = 0; r < 4; ++r) {
      int rr = wr * 64 + mi * 16 + ((lane >> 4) << 2) + r;
      size_t lrow = (size_t)(bm * 128 + rr);
#pragma unroll
      for (int nj = 0; nj < 4; ++nj) {
        int nc = n0 + wc * 64 + nj * 16 + (lane & 15);
        float v = acc[mi][nj][r] + fb[nc];
        v = 0.5f * v * (1.f + erff(v * 0.70710678118654752f));
        hm[lrow * 1536 + nc] = f2bf(v);
      }
    }
  }
}

// ---------------- fc2 GEMM (bf16 MFMA) + residual into out ----------------
__global__ __launch_bounds__(256) void fc2_mfma_k(
    const ushort* __restrict__ hm, const ushort* __restrict__ w2,
    const float* __restrict__ fb, float* __restrict__ out, int row0) {
  __shared__ __align__(16) ushort As[3][4096];
  __shared__ __align__(16) ushort Bs[3][4096];
  const int tid = threadIdx.x;
  const int w = tid >> 6, lane = tid & 63;
  const int wr = w >> 1, wc = w & 1;
  const int bm = blockIdx.x, n0 = blockIdx.y * 128;
  const int rA = w * 32 + (lane >> 2);
  const int sle = (((lane & 3) ^ ((lane >> 3) & 3)) << 4);
  const char* aS0 = (const char*)hm + (size_t)(bm * 128 + rA) * 3072 + sle;
  const char* aS1 = aS0 + (size_t)16 * 3072;
  const char* bS0 = (const char*)w2 + (size_t)(n0 + rA) * 3072 + sle;
  const char* bS1 = bS0 + (size_t)16 * 3072;
  f32x4 acc[4][4];
#pragma unroll
  for (int i = 0; i < 4; ++i)
#pragma unroll
    for (int j = 0; j < 4; ++j) acc[i][j] = (f32x4)(0.f);
  GEMM_PIPE(48);
#pragma unroll
  for (int mi = 0; mi < 4; ++mi) {
#pragma unroll
    for (int r = 0; r < 4; ++r) {
      int rr = wr * 64 + mi * 16 + ((lane >> 4) << 2) + r;
      size_t grow = (size_t)(row0 + bm * 128 + rr);
#pragma unroll
      for (int nj = 0; nj < 4; ++nj) {
        int nc = n0 + wc * 64 + nj * 16 + (lane & 15);
        size_t idx = grow * 384 + nc;
        out[idx] = out[idx] + acc[mi][nj][r] + fb[nc];
      }
    }
  }
}

extern "C" void kernel_launch(void* const* d_in, const int* in_sizes, int n_in,
                              void* d_out, int out_size, void* d_ws, size_t ws_size,
                              hipStream_t stream) {
  const float* x = (const float*)d_in[0];
  const float* qkv_w = (const float*)d_in[1];
  const float* qkv_b = (const float*)d_in[2];
  const float* proj_w = (const float*)d_in[3];
  const float* proj_b = (const float*)d_in[4];
  const float* rpb = (const float*)d_in[5];
  const float* n1g = (const float*)d_in[6];
  const float* n1b = (const float*)d_in[7];
  const float* n2g = (const float*)d_in[8];
  const float* n2b = (const float*)d_in[9];
  const float* fc1w = (const float*)d_in[10];
  const float* fc1b = (const float*)d_in[11];
  const float* fc2w = (const float*)d_in[12];
  const float* fc2b = (const float*)d_in[13];
  float* out = (float*)d_out;
  char* ws = (char*)d_ws;

  float* st1 = (float*)ws;                               // 1 MB
  float* st2 = (float*)(ws + 1048576);                   // 1 MB
  ushort* wq = (ushort*)(ws + 2097152);                  // [1152][384]
  ushort* wp = wq + 442368;                              // [384][384]
  ushort* w1 = wp + 147456;                              // [1536][384]
  ushort* w2 = w1 + 589824;                              // [384][1536]
  ushort* xln = (ushort*)(ws + 5636096);                 // 100663296 B
  char* scratch = ws + 5636096 + 100663296;
  size_t base = 5636096 + 100663296;
  size_t ssz = (ws_size > base) ? ws_size - base : 0;

  wprep_k<<<6912, 256, 0, stream>>>(qkv_w, proj_w, fc1w, fc2w, wq, wp, w1, w2);
  ln_stats_k<<<ROWS_TOTAL / 4, 256, 0, stream>>>(x, st1);
  ln_apply_k<<<ROWS_TOTAL * 48 / 256, 256, 0, stream>>>(x, st1, n1g, n1b, xln);

  // attention phase, chunked over windows
  const size_t perwin = 344064;  // q,k,v fp32 (3*98304B) + ao bf16 (49152B)
  int nwc = (int)(ssz / perwin);
  if (nwc > NWIN_TOTAL) nwc = NWIN_TOTAL;
  nwc &= ~1;
  if (nwc < 2) nwc = 2;
  float* qd = (float*)scratch;
  float* kd = qd + (size_t)nwc * 24576;
  float* vd = kd + (size_t)nwc * 24576;
  ushort* ao = (ushort*)(vd + (size_t)nwc * 24576);
  for (int wc0 = 0; wc0 < NWIN_TOTAL; wc0 += nwc) {
    int nw = (NWIN_TOTAL - wc0 < nwc) ? (NWIN_TOTAL - wc0) : nwc;
    qkv_mfma_k<<<dim3(nw / 2, 9), 256, 0, stream>>>(xln, wq, qkv_b, qd, kd, vd, wc0);
    attn_k<<<dim3(nw, 6), 128, 0, stream>>>(qd, kd, vd, rpb, ao, wc0);
    proj_mfma_k<<<dim3(nw / 2, 3), 256, 0, stream>>>(ao, wp, proj_b, x, out, wc0);
  }

  // MLP phase
  ln_stats_k<<<ROWS_TOTAL / 4, 256, 0, stream>>>(out, st2);
  ln_apply_k<<<ROWS_TOTAL * 48 / 256, 256, 0, stream>>>(out, st2, n2g, n2b, xln);
  const size_t pergrp = 393216;  // 128 rows * 1536 * 2B
  int ngc = (int)(ssz / pergrp);
  if (ngc > 1024) ngc = 1024;
  if (ngc < 1) ngc = 1;
  ushort* hm = (ushort*)scratch;
  for (int g0 = 0; g0 < 1024; g0 += ngc) {
    int ng = (1024 - g0 < ngc) ? (1024 - g0) : ngc;
    fc1_mfma_k<<<dim3(ng, 12), 256, 0, stream>>>(xln, w1, fc1b, hm, g0 * 128);
    fc2_mfma_k<<<dim3(ng, 3), 256, 0, stream>>>(hm, w2, fc2b, out, g0 * 128);
  }
}